// Round 13
// baseline (96.114 us; speedup 1.0000x reference)
//
#include <hip/hip_runtime.h>
#include <hip/hip_bf16.h>
#include <stdint.h>

// SpanMarker, algebraically collapsed:
//   P1 = relu(h@Ws+bs) @ Wo[:D]   (per token, B*L=4096 rows)
//   P2 = relu(h@We+be) @ Wo[D:]
//   out[b,n] = P1[b, is] + P2[b, ie] + bo      (pure gather-add, 151 MB write)
// r10 structure (best, 88.6 µs: 2-phase dbuf GEMMs, plain stores) +
// THIS ROUND: flat no-loop gather (one 64B unit per thread, 9216 blocks).

#define Bsz 8
#define Lsz 512
#define Dsz 768
#define Nsz 6144
#define Mrows (Bsz * Lsz)        // 4096

typedef __attribute__((ext_vector_type(8))) short bf16x8;
typedef __attribute__((ext_vector_type(4))) float f32x4;

#define AS1 __attribute__((address_space(1)))
#define AS3 __attribute__((address_space(3)))

__device__ __forceinline__ void gll16(const void* g, void* l) {
    __builtin_amdgcn_global_load_lds((const AS1 unsigned int*)(uintptr_t)g,
                                     (AS3 unsigned int*)(uintptr_t)l, 16, 0, 0);
}

// ---------------- fused preprocess: h->bf16  +  3 weight transposes ----------------
#define PRE_BLOCKS 5376
__global__ __launch_bounds__(256) void preprocess(const float* __restrict__ h,
                                                  const float* __restrict__ Ws,
                                                  const float* __restrict__ We,
                                                  const float* __restrict__ Wo,
                                                  __hip_bfloat16* __restrict__ hb,
                                                  __hip_bfloat16* __restrict__ Wcat,
                                                  __hip_bfloat16* __restrict__ Wot) {
    int blk = blockIdx.x;
    if (blk < 3072) {
        int i = blk * 256 + threadIdx.x;
        float4 v = reinterpret_cast<const float4*>(h)[i];
        union { __hip_bfloat16 hh[4]; short4 s; } u;
        u.hh[0] = __float2bfloat16(v.x);
        u.hh[1] = __float2bfloat16(v.y);
        u.hh[2] = __float2bfloat16(v.z);
        u.hh[3] = __float2bfloat16(v.w);
        reinterpret_cast<short4*>(hb)[i] = u.s;
        return;
    }
    const float* in;
    __hip_bfloat16* out;
    int R, id;
    if (blk < 3648)      { in = Ws; out = Wcat;                       R = Dsz;     id = blk - 3072; }
    else if (blk < 4224) { in = We; out = Wcat + (size_t)Dsz * Dsz;   R = Dsz;     id = blk - 3648; }
    else                 { in = Wo; out = Wot;                        R = 2 * Dsz; id = blk - 4224; }
    int bx = id % 24, by = id / 24;
    int cb = bx * 32, rb = by * 32;
    __shared__ float tile[32][33];
    int x = threadIdx.x & 31, y0 = threadIdx.x >> 5;
#pragma unroll
    for (int j = 0; j < 4; j++)
        tile[y0 + j * 8][x] = in[(size_t)(rb + y0 + j * 8) * Dsz + cb + x];
    __syncthreads();
#pragma unroll
    for (int j = 0; j < 4; j++)
        out[(size_t)(cb + y0 + j * 8) * R + rb + x] = __float2bfloat16(tile[x][y0 + j * 8]);
}

// ---------------- MFMA tile compute: 64Mx128N tile, 4 waves (2x2), BK=64 ----------------
__device__ __forceinline__ void compute_tile64(const __hip_bfloat16* As, const __hip_bfloat16* Bs,
                                               int lane, int wr, int wc, f32x4 (&acc)[2][4]) {
#pragma unroll
    for (int kk = 0; kk < 64; kk += 32) {
        int ko = kk + 8 * (lane >> 4);
        bf16x8 af[2], bfr[4];
#pragma unroll
        for (int mf = 0; mf < 2; mf++)
            af[mf] = *(const bf16x8*)&As[(wr * 32 + mf * 16 + (lane & 15)) * 64 + ko];
#pragma unroll
        for (int nf = 0; nf < 4; nf++)
            bfr[nf] = *(const bf16x8*)&Bs[(wc * 64 + nf * 16 + (lane & 15)) * 64 + ko];
#pragma unroll
        for (int mf = 0; mf < 2; mf++)
#pragma unroll
            for (int nf = 0; nf < 4; nf++)
                acc[mf][nf] = __builtin_amdgcn_mfma_f32_16x16x32_bf16(af[mf], bfr[nf], acc[mf][nf], 0, 0, 0);
    }
}

// ---------------- GEMM1: SE = relu(hb @ Wcat^T + bias), bf16; 2-phase dbuf ----------------
__global__ __launch_bounds__(256) void gemm1_relu(const __hip_bfloat16* __restrict__ A,
                                                  const __hip_bfloat16* __restrict__ Bt,
                                                  const float* __restrict__ bs,
                                                  const float* __restrict__ be,
                                                  __hip_bfloat16* __restrict__ C) {
    __shared__ __hip_bfloat16 As[2][64 * 64];
    __shared__ __hip_bfloat16 Bs[2][128 * 64];
    int tid = threadIdx.x, lane = tid & 63, wave = tid >> 6;
    int wr = wave >> 1, wc = wave & 1;
    int m0 = blockIdx.x * 64, n0 = blockIdx.y * 128;
    int r = tid >> 3, c8 = (tid & 7) * 8;

    const __hip_bfloat16* ga[2];
    const __hip_bfloat16* gb[4];
#pragma unroll
    for (int i = 0; i < 2; i++)
        ga[i] = A + (size_t)(m0 + r + i * 32) * Dsz + c8;
#pragma unroll
    for (int i = 0; i < 4; i++)
        gb[i] = Bt + (size_t)(n0 + r + i * 32) * Dsz + c8;

    f32x4 acc[2][4];
#pragma unroll
    for (int mf = 0; mf < 2; mf++)
#pragma unroll
        for (int nf = 0; nf < 4; nf++) acc[mf][nf] = (f32x4){0.f, 0.f, 0.f, 0.f};

#define STAGE1(buf, kt)                                                          \
    do {                                                                         \
        _Pragma("unroll")                                                        \
        for (int i = 0; i < 2; i++) gll16(ga[i] + (kt), &As[buf][(i * 256 + tid) * 8]); \
        _Pragma("unroll")                                                        \
        for (int i = 0; i < 4; i++) gll16(gb[i] + (kt), &Bs[buf][(i * 256 + tid) * 8]); \
    } while (0)

    STAGE1(0, 0);
    __syncthreads();
    int cur = 0;
    for (int t = 0; t < Dsz / 64 - 1; ++t) {
        STAGE1(cur ^ 1, (t + 1) * 64);
        compute_tile64(As[cur], Bs[cur], lane, wr, wc, acc);
        __syncthreads();
        cur ^= 1;
    }
    compute_tile64(As[cur], Bs[cur], lane, wr, wc, acc);
#undef STAGE1

#pragma unroll
    for (int mf = 0; mf < 2; mf++) {
        int r0 = m0 + wr * 32 + mf * 16 + (lane >> 4) * 4;
#pragma unroll
        for (int nf = 0; nf < 4; nf++) {
            int col = n0 + wc * 64 + nf * 16 + (lane & 15);
            float bv = col < Dsz ? bs[col] : be[col - Dsz];
#pragma unroll
            for (int rg = 0; rg < 4; rg++) {
                float v = acc[mf][nf][rg] + bv;
                v = v > 0.f ? v : 0.f;
                C[(size_t)(r0 + rg) * (2 * Dsz) + col] = __float2bfloat16(v);
            }
        }
    }
}

// ---------------- GEMM2: P[z] = SE-half @ Wot-half^T, bf16; 2-phase dbuf ----------------
__global__ __launch_bounds__(256) void gemm2_nt(const __hip_bfloat16* __restrict__ SE,
                                                const __hip_bfloat16* __restrict__ Wot,
                                                __hip_bfloat16* __restrict__ P) {
    __shared__ __hip_bfloat16 As[2][64 * 64];
    __shared__ __hip_bfloat16 Bs[2][128 * 64];
    int tid = threadIdx.x, lane = tid & 63, wave = tid >> 6;
    int wr = wave >> 1, wc = wave & 1;
    int m0 = blockIdx.x * 64, n0 = blockIdx.y * 128;
    int z = blockIdx.z;
    int koff = z * Dsz;
    int r = tid >> 3, c8 = (tid & 7) * 8;

    const __hip_bfloat16* ga[2];
    const __hip_bfloat16* gb[4];
#pragma unroll
    for (int i = 0; i < 2; i++)
        ga[i] = SE + (size_t)(m0 + r + i * 32) * (2 * Dsz) + koff + c8;
#pragma unroll
    for (int i = 0; i < 4; i++)
        gb[i] = Wot + (size_t)(n0 + r + i * 32) * (2 * Dsz) + koff + c8;

    f32x4 acc[2][4];
#pragma unroll
    for (int mf = 0; mf < 2; mf++)
#pragma unroll
        for (int nf = 0; nf < 4; nf++) acc[mf][nf] = (f32x4){0.f, 0.f, 0.f, 0.f};

#define STAGE2(buf, kt)                                                          \
    do {                                                                         \
        _Pragma("unroll")                                                        \
        for (int i = 0; i < 2; i++) gll16(ga[i] + (kt), &As[buf][(i * 256 + tid) * 8]); \
        _Pragma("unroll")                                                        \
        for (int i = 0; i < 4; i++) gll16(gb[i] + (kt), &Bs[buf][(i * 256 + tid) * 8]); \
    } while (0)

    STAGE2(0, 0);
    __syncthreads();
    int cur = 0;
    for (int t = 0; t < Dsz / 64 - 1; ++t) {
        STAGE2(cur ^ 1, (t + 1) * 64);
        compute_tile64(As[cur], Bs[cur], lane, wr, wc, acc);
        __syncthreads();
        cur ^= 1;
    }
    compute_tile64(As[cur], Bs[cur], lane, wr, wc, acc);
#undef STAGE2

    __hip_bfloat16* Pz = P + (size_t)z * Mrows * Dsz;
#pragma unroll
    for (int mf = 0; mf < 2; mf++) {
        int r0 = m0 + wr * 32 + mf * 16 + (lane >> 4) * 4;
#pragma unroll
        for (int nf = 0; nf < 4; nf++) {
            int col = n0 + wc * 64 + nf * 16 + (lane & 15);
#pragma unroll
            for (int rg = 0; rg < 4; rg++)
                Pz[(size_t)(r0 + rg) * Dsz + col] = __float2bfloat16(acc[mf][nf][rg]);
        }
    }
}

// ---------------- gather-add: flat grid, one 16-float unit per thread ----------------
// unit u -> row r = u/48, feature d = (u%48)*16. 9216 blocks x 256 threads
// cover exactly 49152 rows x 48 units. Reads 2x32B (P1,P2 rows), writes 64B.
#define GA_FLAT_BLOCKS (Bsz * Nsz * 48 / 256)   // 9216
__global__ __launch_bounds__(256) void gather_add(const __hip_bfloat16* __restrict__ P,
                                                  const int* __restrict__ span_idx,
                                                  const float* __restrict__ bo,
                                                  float* __restrict__ out) {
    int u = blockIdx.x * 256 + threadIdx.x;
    int r = u / 48;               // global span row, 0..49151
    int d = (u % 48) * 16;        // feature offset
    int b = r / Nsz;
    int is = span_idx[2 * r];
    int ie = span_idx[2 * r + 1];
    const __hip_bfloat16* p1p = &P[((size_t)(b * Lsz + is)) * Dsz + d];
    const __hip_bfloat16* p2p = &P[((size_t)(Mrows + b * Lsz + ie)) * Dsz + d];
    bf16x8 p1a = *(const bf16x8*)p1p;
    bf16x8 p1b = *(const bf16x8*)(p1p + 8);
    bf16x8 p2a = *(const bf16x8*)p2p;
    bf16x8 p2b = *(const bf16x8*)(p2p + 8);
    union { unsigned int u32; float f; } cv;
#define CVT(x) (cv.u32 = ((unsigned int)(unsigned short)(x)) << 16, cv.f)
    float* op = &out[(size_t)r * Dsz + d];
    f32x4 o;
#pragma unroll
    for (int q = 0; q < 2; ++q) {
        const bf16x8& a1 = q ? p1b : p1a;
        const bf16x8& a2 = q ? p2b : p2a;
#pragma unroll
        for (int hhalf = 0; hhalf < 2; ++hhalf) {
            int base = hhalf * 4;
            const float* bop = &bo[d + q * 8 + hhalf * 4];
            o[0] = CVT(a1[base + 0]) + CVT(a2[base + 0]) + bop[0];
            o[1] = CVT(a1[base + 1]) + CVT(a2[base + 1]) + bop[1];
            o[2] = CVT(a1[base + 2]) + CVT(a2[base + 2]) + bop[2];
            o[3] = CVT(a1[base + 3]) + CVT(a2[base + 3]) + bop[3];
            *(f32x4*)(op + q * 8 + hhalf * 4) = o;
        }
    }
#undef CVT
}

extern "C" void kernel_launch(void* const* d_in, const int* in_sizes, int n_in,
                              void* d_out, int out_size, void* d_ws, size_t ws_size,
                              hipStream_t stream) {
    const float* h        = (const float*)d_in[0];
    const int*   span_idx = (const int*)d_in[1];
    const float* Ws       = (const float*)d_in[2];
    const float* bs       = (const float*)d_in[3];
    const float* We       = (const float*)d_in[4];
    const float* be       = (const float*)d_in[5];
    const float* Wo       = (const float*)d_in[6];
    const float* bo       = (const float*)d_in[7];
    float* out            = (float*)d_out;

    // workspace (bf16): hb[4096*768] | Wcat[1536*768] | Wot[768*1536] | SE[4096*1536] | P[2*4096*768]
    __hip_bfloat16* hb   = (__hip_bfloat16*)d_ws;
    __hip_bfloat16* Wcat = hb + (size_t)Mrows * Dsz;
    __hip_bfloat16* Wot  = Wcat + (size_t)2 * Dsz * Dsz;
    __hip_bfloat16* SE   = Wot + (size_t)Dsz * 2 * Dsz;
    __hip_bfloat16* P    = SE + (size_t)Mrows * 2 * Dsz;

    // fused: h->bf16, Ws^T|We^T -> Wcat, Wo^T -> Wot
    preprocess<<<PRE_BLOCKS, 256, 0, stream>>>(h, Ws, We, Wo, hb, Wcat, Wot);

    // SE = relu(h @ [Ws|We] + [bs|be])   (M=4096, N=1536, K=768), grid 64x12=768
    gemm1_relu<<<dim3(Mrows / 64, 2 * Dsz / 128), 256, 0, stream>>>(hb, Wcat, bs, be, SE);

    // P[z] = SE[:, z-half] @ Wo[z-half]   (M=4096, N=768, K=768) x2, grid 64x6x2=768
    gemm2_nt<<<dim3(Mrows / 64, Dsz / 128, 2), 256, 0, stream>>>(SE, Wot, P);

    // out[b,n] = P1[b,is] + P2[b,ie] + bo   (flat, one 64B unit/thread)
    gather_add<<<GA_FLAT_BLOCKS, 256, 0, stream>>>(P, span_idx, bo, out);
}

// Round 14
// 88.375 us; speedup vs baseline: 1.0876x; 1.0876x over previous
//
#include <hip/hip_runtime.h>
#include <hip/hip_bf16.h>
#include <stdint.h>

// SpanMarker, algebraically collapsed:
//   P1 = relu(h@Ws+bs) @ Wo[:D]   (per token, B*L=4096 rows)
//   P2 = relu(h@We+be) @ Wo[D:]
//   out[b,n] = P1[b, is] + P2[b, ie] + bo      (pure gather-add, 151 MB write)
// r10 structure (best, 88.6 µs) + THIS ROUND: Wo^T transpose moved from
// preprocess into gemm1's dispatch (blocks 768..1919) — Wot is only needed
// by gemm2, so ordering is preserved; transpose work hides in gemm1's tail.

#define Bsz 8
#define Lsz 512
#define Dsz 768
#define Nsz 6144
#define Mrows (Bsz * Lsz)        // 4096

typedef __attribute__((ext_vector_type(8))) short bf16x8;
typedef __attribute__((ext_vector_type(4))) float f32x4;

#define AS1 __attribute__((address_space(1)))
#define AS3 __attribute__((address_space(3)))

__device__ __forceinline__ void gll16(const void* g, void* l) {
    __builtin_amdgcn_global_load_lds((const AS1 unsigned int*)(uintptr_t)g,
                                     (AS3 unsigned int*)(uintptr_t)l, 16, 0, 0);
}

// ---------------- preprocess: h->bf16 + Ws^T|We^T -> Wcat (Wo^T moved to gemm1) ----------------
#define PRE_BLOCKS 4224
__global__ __launch_bounds__(256) void preprocess(const float* __restrict__ h,
                                                  const float* __restrict__ Ws,
                                                  const float* __restrict__ We,
                                                  __hip_bfloat16* __restrict__ hb,
                                                  __hip_bfloat16* __restrict__ Wcat) {
    int blk = blockIdx.x;
    if (blk < 3072) {
        int i = blk * 256 + threadIdx.x;
        float4 v = reinterpret_cast<const float4*>(h)[i];
        union { __hip_bfloat16 hh[4]; short4 s; } u;
        u.hh[0] = __float2bfloat16(v.x);
        u.hh[1] = __float2bfloat16(v.y);
        u.hh[2] = __float2bfloat16(v.z);
        u.hh[3] = __float2bfloat16(v.w);
        reinterpret_cast<short4*>(hb)[i] = u.s;
        return;
    }
    const float* in;
    __hip_bfloat16* out;
    int id;
    if (blk < 3648) { in = Ws; out = Wcat;                     id = blk - 3072; }
    else            { in = We; out = Wcat + (size_t)Dsz * Dsz; id = blk - 3648; }
    int bx = id % 24, by = id / 24;
    int cb = bx * 32, rb = by * 32;
    __shared__ float tile[32][33];
    int x = threadIdx.x & 31, y0 = threadIdx.x >> 5;
#pragma unroll
    for (int j = 0; j < 4; j++)
        tile[y0 + j * 8][x] = in[(size_t)(rb + y0 + j * 8) * Dsz + cb + x];
    __syncthreads();
#pragma unroll
    for (int j = 0; j < 4; j++)
        out[(size_t)(cb + y0 + j * 8) * Dsz + rb + x] = __float2bfloat16(tile[x][y0 + j * 8]);
}

// ---------------- MFMA tile compute: 64Mx128N tile, 4 waves (2x2), BK=64 ----------------
__device__ __forceinline__ void compute_tile64(const __hip_bfloat16* As, const __hip_bfloat16* Bs,
                                               int lane, int wr, int wc, f32x4 (&acc)[2][4]) {
#pragma unroll
    for (int kk = 0; kk < 64; kk += 32) {
        int ko = kk + 8 * (lane >> 4);
        bf16x8 af[2], bfr[4];
#pragma unroll
        for (int mf = 0; mf < 2; mf++)
            af[mf] = *(const bf16x8*)&As[(wr * 32 + mf * 16 + (lane & 15)) * 64 + ko];
#pragma unroll
        for (int nf = 0; nf < 4; nf++)
            bfr[nf] = *(const bf16x8*)&Bs[(wc * 64 + nf * 16 + (lane & 15)) * 64 + ko];
#pragma unroll
        for (int mf = 0; mf < 2; mf++)
#pragma unroll
            for (int nf = 0; nf < 4; nf++)
                acc[mf][nf] = __builtin_amdgcn_mfma_f32_16x16x32_bf16(af[mf], bfr[nf], acc[mf][nf], 0, 0, 0);
    }
}

// ---------------- GEMM1 (+Wo^T): blocks 0..767 gemm1 tiles, 768..1919 Wo transpose ----------------
#define G1_BLOCKS (768 + 1152)
__global__ __launch_bounds__(256) void gemm1_relu(const __hip_bfloat16* __restrict__ A,
                                                  const __hip_bfloat16* __restrict__ Bt,
                                                  const float* __restrict__ bs,
                                                  const float* __restrict__ be,
                                                  const float* __restrict__ Wo,
                                                  __hip_bfloat16* __restrict__ Wot,
                                                  __hip_bfloat16* __restrict__ C) {
    __shared__ __hip_bfloat16 As[2][64 * 64];
    __shared__ __hip_bfloat16 Bs[2][128 * 64];
    int tid = threadIdx.x;
    int blk = blockIdx.x;

    if (blk >= 768) {
        // Wo^T tile: in Wo[1536][768] -> Wot[768][1536]
        int id = blk - 768;                       // 0..1151 (24 x 48)
        int cb = (id % 24) * 32, rb = (id / 24) * 32;
        float (*tile)[33] = (float(*)[33])(&As[0][0]);   // reuse GEMM LDS
        int x = tid & 31, y0 = tid >> 5;
#pragma unroll
        for (int j = 0; j < 4; j++)
            tile[y0 + j * 8][x] = Wo[(size_t)(rb + y0 + j * 8) * Dsz + cb + x];
        __syncthreads();
#pragma unroll
        for (int j = 0; j < 4; j++)
            Wot[(size_t)(cb + y0 + j * 8) * (2 * Dsz) + rb + x] = __float2bfloat16(tile[x][y0 + j * 8]);
        return;
    }

    int lane = tid & 63, wave = tid >> 6;
    int wr = wave >> 1, wc = wave & 1;
    int m0 = (blk & 63) * 64, n0 = (blk >> 6) * 128;
    int r = tid >> 3, c8 = (tid & 7) * 8;

    const __hip_bfloat16* ga[2];
    const __hip_bfloat16* gb[4];
#pragma unroll
    for (int i = 0; i < 2; i++)
        ga[i] = A + (size_t)(m0 + r + i * 32) * Dsz + c8;
#pragma unroll
    for (int i = 0; i < 4; i++)
        gb[i] = Bt + (size_t)(n0 + r + i * 32) * Dsz + c8;

    f32x4 acc[2][4];
#pragma unroll
    for (int mf = 0; mf < 2; mf++)
#pragma unroll
        for (int nf = 0; nf < 4; nf++) acc[mf][nf] = (f32x4){0.f, 0.f, 0.f, 0.f};

#define STAGE1(buf, kt)                                                          \
    do {                                                                         \
        _Pragma("unroll")                                                        \
        for (int i = 0; i < 2; i++) gll16(ga[i] + (kt), &As[buf][(i * 256 + tid) * 8]); \
        _Pragma("unroll")                                                        \
        for (int i = 0; i < 4; i++) gll16(gb[i] + (kt), &Bs[buf][(i * 256 + tid) * 8]); \
    } while (0)

    STAGE1(0, 0);
    __syncthreads();
    int cur = 0;
    for (int t = 0; t < Dsz / 64 - 1; ++t) {
        STAGE1(cur ^ 1, (t + 1) * 64);
        compute_tile64(As[cur], Bs[cur], lane, wr, wc, acc);
        __syncthreads();
        cur ^= 1;
    }
    compute_tile64(As[cur], Bs[cur], lane, wr, wc, acc);
#undef STAGE1

#pragma unroll
    for (int mf = 0; mf < 2; mf++) {
        int r0 = m0 + wr * 32 + mf * 16 + (lane >> 4) * 4;
#pragma unroll
        for (int nf = 0; nf < 4; nf++) {
            int col = n0 + wc * 64 + nf * 16 + (lane & 15);
            float bv = col < Dsz ? bs[col] : be[col - Dsz];
#pragma unroll
            for (int rg = 0; rg < 4; rg++) {
                float v = acc[mf][nf][rg] + bv;
                v = v > 0.f ? v : 0.f;
                C[(size_t)(r0 + rg) * (2 * Dsz) + col] = __float2bfloat16(v);
            }
        }
    }
}

// ---------------- GEMM2: P[z] = SE-half @ Wot-half^T, bf16; 2-phase dbuf ----------------
__global__ __launch_bounds__(256) void gemm2_nt(const __hip_bfloat16* __restrict__ SE,
                                                const __hip_bfloat16* __restrict__ Wot,
                                                __hip_bfloat16* __restrict__ P) {
    __shared__ __hip_bfloat16 As[2][64 * 64];
    __shared__ __hip_bfloat16 Bs[2][128 * 64];
    int tid = threadIdx.x, lane = tid & 63, wave = tid >> 6;
    int wr = wave >> 1, wc = wave & 1;
    int m0 = blockIdx.x * 64, n0 = blockIdx.y * 128;
    int z = blockIdx.z;
    int koff = z * Dsz;
    int r = tid >> 3, c8 = (tid & 7) * 8;

    const __hip_bfloat16* ga[2];
    const __hip_bfloat16* gb[4];
#pragma unroll
    for (int i = 0; i < 2; i++)
        ga[i] = SE + (size_t)(m0 + r + i * 32) * (2 * Dsz) + koff + c8;
#pragma unroll
    for (int i = 0; i < 4; i++)
        gb[i] = Wot + (size_t)(n0 + r + i * 32) * (2 * Dsz) + koff + c8;

    f32x4 acc[2][4];
#pragma unroll
    for (int mf = 0; mf < 2; mf++)
#pragma unroll
        for (int nf = 0; nf < 4; nf++) acc[mf][nf] = (f32x4){0.f, 0.f, 0.f, 0.f};

#define STAGE2(buf, kt)                                                          \
    do {                                                                         \
        _Pragma("unroll")                                                        \
        for (int i = 0; i < 2; i++) gll16(ga[i] + (kt), &As[buf][(i * 256 + tid) * 8]); \
        _Pragma("unroll")                                                        \
        for (int i = 0; i < 4; i++) gll16(gb[i] + (kt), &Bs[buf][(i * 256 + tid) * 8]); \
    } while (0)

    STAGE2(0, 0);
    __syncthreads();
    int cur = 0;
    for (int t = 0; t < Dsz / 64 - 1; ++t) {
        STAGE2(cur ^ 1, (t + 1) * 64);
        compute_tile64(As[cur], Bs[cur], lane, wr, wc, acc);
        __syncthreads();
        cur ^= 1;
    }
    compute_tile64(As[cur], Bs[cur], lane, wr, wc, acc);
#undef STAGE2

    __hip_bfloat16* Pz = P + (size_t)z * Mrows * Dsz;
#pragma unroll
    for (int mf = 0; mf < 2; mf++) {
        int r0 = m0 + wr * 32 + mf * 16 + (lane >> 4) * 4;
#pragma unroll
        for (int nf = 0; nf < 4; nf++) {
            int col = n0 + wc * 64 + nf * 16 + (lane & 15);
#pragma unroll
            for (int rg = 0; rg < 4; rg++)
                Pz[(size_t)(r0 + rg) * Dsz + col] = __float2bfloat16(acc[mf][nf][rg]);
        }
    }
}

// ---------------- gather-add: out[r] = P1[b,is] + P2[b,ie] + bo  (plain cached stores) ----------------
#define GA_BLOCKS 2304
#define GA_TOT (Bsz * Nsz * 96)   // 96 chunks of 8 floats per row
__global__ __launch_bounds__(256) void gather_add(const __hip_bfloat16* __restrict__ P,
                                                  const int* __restrict__ span_idx,
                                                  const float* __restrict__ bo,
                                                  float* __restrict__ out) {
    for (int u = blockIdx.x * 256 + threadIdx.x; u < GA_TOT; u += GA_BLOCKS * 256) {
        int r = u / 96;           // global span row, 0..49151
        int d = (u % 96) * 8;     // feature offset
        int b = r / Nsz;
        int is = span_idx[2 * r];
        int ie = span_idx[2 * r + 1];
        const bf16x8 p1 = *(const bf16x8*)&P[((size_t)(b * Lsz + is)) * Dsz + d];
        const bf16x8 p2 = *(const bf16x8*)&P[((size_t)(Mrows + b * Lsz + ie)) * Dsz + d];
        f32x4 b0 = *(const f32x4*)&bo[d];
        f32x4 b1 = *(const f32x4*)&bo[d + 4];
        f32x4 o0, o1;
        union { unsigned int u32; float f; } cv;
#define CVT(x) (cv.u32 = ((unsigned int)(unsigned short)(x)) << 16, cv.f)
        o0[0] = CVT(p1[0]) + CVT(p2[0]) + b0[0];
        o0[1] = CVT(p1[1]) + CVT(p2[1]) + b0[1];
        o0[2] = CVT(p1[2]) + CVT(p2[2]) + b0[2];
        o0[3] = CVT(p1[3]) + CVT(p2[3]) + b0[3];
        o1[0] = CVT(p1[4]) + CVT(p2[4]) + b1[0];
        o1[1] = CVT(p1[5]) + CVT(p2[5]) + b1[1];
        o1[2] = CVT(p1[6]) + CVT(p2[6]) + b1[2];
        o1[3] = CVT(p1[7]) + CVT(p2[7]) + b1[3];
#undef CVT
        float* op = &out[(size_t)r * Dsz + d];
        *(f32x4*)op = o0;
        *(f32x4*)(op + 4) = o1;
    }
}

extern "C" void kernel_launch(void* const* d_in, const int* in_sizes, int n_in,
                              void* d_out, int out_size, void* d_ws, size_t ws_size,
                              hipStream_t stream) {
    const float* h        = (const float*)d_in[0];
    const int*   span_idx = (const int*)d_in[1];
    const float* Ws       = (const float*)d_in[2];
    const float* bs       = (const float*)d_in[3];
    const float* We       = (const float*)d_in[4];
    const float* be       = (const float*)d_in[5];
    const float* Wo       = (const float*)d_in[6];
    const float* bo       = (const float*)d_in[7];
    float* out            = (float*)d_out;

    // workspace (bf16): hb[4096*768] | Wcat[1536*768] | Wot[768*1536] | SE[4096*1536] | P[2*4096*768]
    __hip_bfloat16* hb   = (__hip_bfloat16*)d_ws;
    __hip_bfloat16* Wcat = hb + (size_t)Mrows * Dsz;
    __hip_bfloat16* Wot  = Wcat + (size_t)2 * Dsz * Dsz;
    __hip_bfloat16* SE   = Wot + (size_t)Dsz * 2 * Dsz;
    __hip_bfloat16* P    = SE + (size_t)Mrows * 2 * Dsz;

    // h->bf16, Ws^T|We^T -> Wcat  (Wo^T moved into gemm1's dispatch)
    preprocess<<<PRE_BLOCKS, 256, 0, stream>>>(h, Ws, We, hb, Wcat);

    // SE = relu(h @ [Ws|We] + [bs|be])  + Wo^T side-blocks   (grid 1920)
    gemm1_relu<<<G1_BLOCKS, 256, 0, stream>>>(hb, Wcat, bs, be, Wo, Wot, SE);

    // P[z] = SE[:, z-half] @ Wo[z-half]   (M=4096, N=768, K=768) x2, grid 64x6x2=768
    gemm2_nt<<<dim3(Mrows / 64, Dsz / 128, 2), 256, 0, stream>>>(SE, Wot, P);

    // out[b,n] = P1[b,is] + P2[b,ie] + bo
    gather_add<<<GA_BLOCKS, 256, 0, stream>>>(P, span_idx, bo, out);
}